// Round 1
// baseline (263.568 us; speedup 1.0000x reference)
//
#include <hip/hip_runtime.h>

// Integrate-and-fire SNN forward (IF_88957362634870).
// x: (T1*B, C, H, W) fp32, viewed as T1 frames of N = B*C*H*W elements.
// out: (T2*B, C, H, W) fp32, T2 frames of N elements.
// Pure elementwise recurrence over spatial index -> one thread per float4
// group of 4 elements. Memory-bound: 128 MiB read + 128 MiB write.

#define T1 8
#define T2 8
#define L_DIV 8.0f
#define EPS_C (-8e-05f)

__global__ __launch_bounds__(256) void if_fwd_kernel(
    const float4* __restrict__ x,
    const float* __restrict__ thresh,
    float4* __restrict__ out,
    int n4)   // N/4, number of float4 groups per frame
{
    const int i = blockIdx.x * blockDim.x + threadIdx.x;
    if (i >= n4) return;

    const float thre = thresh[0] / L_DIV;

    float m[4], sc[4];
    #pragma unroll
    for (int k = 0; k < 4; ++k) { m[k] = 0.5f * thre; sc[k] = 0.0f; }

    // Phase 1: integrate the T1 input frames (fire-and-subtract each step)
    #pragma unroll
    for (int t = 0; t < T1; ++t) {
        const float4 xt = x[(size_t)t * n4 + i];
        const float xs[4] = {xt.x, xt.y, xt.z, xt.w};
        #pragma unroll
        for (int k = 0; k < 4; ++k) {
            m[k] += xs[k];
            const float spike = (m[k] - thre >= EPS_C) ? thre : 0.0f;
            m[k] -= spike;
            sc[k] += spike;
        }
    }

    // Phase 2: T3-1 = 7 relaxation steps with reverse spikes (register-only)
    #pragma unroll
    for (int t = 0; t < T1 - 1; ++t) {
        #pragma unroll
        for (int k = 0; k < 4; ++k) {
            const float spike = (m[k] - thre >= EPS_C) ? thre : 0.0f;
            const float rev   = (-m[k] > 0.0f) ? thre : 0.0f;
            m[k] = m[k] - spike + rev;
            sc[k] += spike - rev;
        }
    }

    // Phase 3: re-emit spike count as T2 output frames
    #pragma unroll
    for (int t = 0; t < T2; ++t) {
        float os[4];
        #pragma unroll
        for (int k = 0; k < 4; ++k) {
            const float spike = (sc[k] - thre >= EPS_C) ? thre : 0.0f;
            os[k] = spike;
            sc[k] -= spike;
        }
        float4 o;
        o.x = os[0]; o.y = os[1]; o.z = os[2]; o.w = os[3];
        out[(size_t)t * n4 + i] = o;
    }
}

extern "C" void kernel_launch(void* const* d_in, const int* in_sizes, int n_in,
                              void* d_out, int out_size, void* d_ws, size_t ws_size,
                              hipStream_t stream) {
    const float4* x      = (const float4*)d_in[0];
    const float*  thresh = (const float*)d_in[1];
    float4*       out    = (float4*)d_out;

    const int N  = in_sizes[0] / T1;  // B*C*H*W = 4,194,304
    const int n4 = N / 4;             // 1,048,576 float4 groups per frame

    const int block = 256;
    const int grid  = (n4 + block - 1) / block;  // 4096
    if_fwd_kernel<<<grid, block, 0, stream>>>(x, thresh, out, n4);
}

// Round 3
// 244.461 us; speedup vs baseline: 1.0782x; 1.0782x over previous
//
#include <hip/hip_runtime.h>

// Integrate-and-fire SNN forward (IF_88957362634870).
// x: (T1*B, C, H, W) fp32 = 8 frames of N = 4,194,304 elements (16 MiB each).
// out: 8 frames of N elements.
// Elementwise recurrence -> 1 thread per 4-element group.
// R1 theory: load ALL 8 frames into registers up front (8 independent
// global_load_dwordx4 in flight per wave -> 8x MLP vs R0's serialized chain
// at VGPR=20), compute in registers, then 8 nontemporal stores (output never
// re-read; keep L3 for the input, cut write amplification).
// R2 fix: __builtin_nontemporal_store needs a native vector type, not the
// HIP float4 class -> use ext_vector_type(4).

#define T1 8
#define T2 8
#define L_DIV 8.0f
#define EPS_C (-8e-05f)

typedef float fvec4 __attribute__((ext_vector_type(4)));

__global__ __launch_bounds__(256) void if_fwd_kernel(
    const fvec4* __restrict__ x,
    const float* __restrict__ thresh,
    fvec4* __restrict__ out,
    int n4)   // N/4 groups per frame
{
    const int i = blockIdx.x * blockDim.x + threadIdx.x;
    if (i >= n4) return;

    const float thre = thresh[0] / L_DIV;

    // Issue all 8 frame loads back-to-back (independent -> 8 outstanding).
    fvec4 xv[T1];
    #pragma unroll
    for (int t = 0; t < T1; ++t) {
        xv[t] = x[(size_t)t * n4 + i];
    }

    float m[4], sc[4];
    #pragma unroll
    for (int k = 0; k < 4; ++k) { m[k] = 0.5f * thre; sc[k] = 0.0f; }

    // Phase 1: integrate T1 frames, fire-and-subtract.
    #pragma unroll
    for (int t = 0; t < T1; ++t) {
        #pragma unroll
        for (int k = 0; k < 4; ++k) {
            m[k] += xv[t][k];
            const float spike = (m[k] - thre >= EPS_C) ? thre : 0.0f;
            m[k] -= spike;
            sc[k] += spike;
        }
    }

    // Phase 2: 7 relaxation steps with reverse spikes (register-only).
    #pragma unroll
    for (int t = 0; t < T1 - 1; ++t) {
        #pragma unroll
        for (int k = 0; k < 4; ++k) {
            const float spike = (m[k] - thre >= EPS_C) ? thre : 0.0f;
            const float rev   = (-m[k] > 0.0f) ? thre : 0.0f;
            m[k] = m[k] - spike + rev;
            sc[k] += spike - rev;
        }
    }

    // Phase 3: emit T2 output frames from the spike count.
    #pragma unroll
    for (int t = 0; t < T2; ++t) {
        fvec4 o;
        #pragma unroll
        for (int k = 0; k < 4; ++k) {
            const float spike = (sc[k] - thre >= EPS_C) ? thre : 0.0f;
            o[k] = spike;
            sc[k] -= spike;
        }
        __builtin_nontemporal_store(o, &out[(size_t)t * n4 + i]);
    }
}

extern "C" void kernel_launch(void* const* d_in, const int* in_sizes, int n_in,
                              void* d_out, int out_size, void* d_ws, size_t ws_size,
                              hipStream_t stream) {
    const fvec4* x      = (const fvec4*)d_in[0];
    const float* thresh = (const float*)d_in[1];
    fvec4*       out    = (fvec4*)d_out;

    const int N  = in_sizes[0] / T1;  // 4,194,304
    const int n4 = N / 4;             // 1,048,576

    const int block = 256;
    const int grid  = (n4 + block - 1) / block;  // 4096
    if_fwd_kernel<<<grid, block, 0, stream>>>(x, thresh, out, n4);
}

// Round 4
// 238.557 us; speedup vs baseline: 1.1048x; 1.0247x over previous
//
#include <hip/hip_runtime.h>

// Integrate-and-fire SNN forward (IF_88957362634870).
// x: 8 frames of N = 4,194,304 fp32 (16 MiB each); out: 8 frames.
// Elementwise recurrence. HBM traffic floor ~196 MB (65 MB fetch w/ L3
// residency + 131 MB nontemporal write) -> ~31 us at 6.3 TB/s.
//
// R3 finding: compiler sank the 8 up-front loads to their uses (VGPR=20,
// <=2 outstanding loads, latency-bound at 2 TB/s).
// R4 fix: (a) sched_barrier(0) after the load block forces all loads to
// issue before any compute (all frames pinned live in VGPRs);
// (b) 2 independent spatial groups per thread -> 16 outstanding
// global_load_dwordx4 per wave + dual independent ALU chains.

#define T1 8
#define T2 8
#define L_DIV 8.0f
#define EPS_C (-8e-05f)
#define G 2            // spatial float4-groups per thread

typedef float fvec4 __attribute__((ext_vector_type(4)));

__global__ __launch_bounds__(256) void if_fwd_kernel(
    const fvec4* __restrict__ x,
    const float* __restrict__ thresh,
    fvec4* __restrict__ out,
    int n4)   // N/4 groups per frame
{
    // Block-strided pair: thread handles groups base and base+256.
    const int base = blockIdx.x * (blockDim.x * G) + threadIdx.x;

    const float thre = thresh[0] / L_DIV;

    // ---- Issue all T1*G loads back-to-back, then fence scheduling ----
    fvec4 xv[G][T1];
    #pragma unroll
    for (int t = 0; t < T1; ++t) {
        #pragma unroll
        for (int g = 0; g < G; ++g) {
            xv[g][t] = x[(size_t)t * n4 + base + g * 256];
        }
    }
    __builtin_amdgcn_sched_barrier(0);  // nothing crosses: loads stay hoisted

    float m[G][4], sc[G][4];
    #pragma unroll
    for (int g = 0; g < G; ++g)
        #pragma unroll
        for (int k = 0; k < 4; ++k) { m[g][k] = 0.5f * thre; sc[g][k] = 0.0f; }

    // Phase 1: integrate T1 frames, fire-and-subtract.
    #pragma unroll
    for (int t = 0; t < T1; ++t) {
        #pragma unroll
        for (int g = 0; g < G; ++g) {
            #pragma unroll
            for (int k = 0; k < 4; ++k) {
                m[g][k] += xv[g][t][k];
                const float spike = (m[g][k] - thre >= EPS_C) ? thre : 0.0f;
                m[g][k] -= spike;
                sc[g][k] += spike;
            }
        }
    }

    // Phase 2: 7 relaxation steps with reverse spikes (register-only).
    #pragma unroll
    for (int t = 0; t < T1 - 1; ++t) {
        #pragma unroll
        for (int g = 0; g < G; ++g) {
            #pragma unroll
            for (int k = 0; k < 4; ++k) {
                const float spike = (m[g][k] - thre >= EPS_C) ? thre : 0.0f;
                const float rev   = (-m[g][k] > 0.0f) ? thre : 0.0f;
                m[g][k] = m[g][k] - spike + rev;
                sc[g][k] += spike - rev;
            }
        }
    }

    // Phase 3: emit T2 output frames from the spike count.
    #pragma unroll
    for (int t = 0; t < T2; ++t) {
        #pragma unroll
        for (int g = 0; g < G; ++g) {
            fvec4 o;
            #pragma unroll
            for (int k = 0; k < 4; ++k) {
                const float spike = (sc[g][k] - thre >= EPS_C) ? thre : 0.0f;
                o[k] = spike;
                sc[g][k] -= spike;
            }
            __builtin_nontemporal_store(o, &out[(size_t)t * n4 + base + g * 256]);
        }
    }
}

extern "C" void kernel_launch(void* const* d_in, const int* in_sizes, int n_in,
                              void* d_out, int out_size, void* d_ws, size_t ws_size,
                              hipStream_t stream) {
    const fvec4* x      = (const fvec4*)d_in[0];
    const float* thresh = (const float*)d_in[1];
    fvec4*       out    = (fvec4*)d_out;

    const int N  = in_sizes[0] / T1;  // 4,194,304
    const int n4 = N / 4;             // 1,048,576

    const int block = 256;
    const int grid  = n4 / (block * G);  // 2048, exact
    if_fwd_kernel<<<grid, block, 0, stream>>>(x, thresh, out, n4);
}